// Round 3
// baseline (65.731 us; speedup 1.0000x reference)
//
#include <hip/hip_runtime.h>
#include <hip/hip_bf16.h>

#define NBINS 20
#define NCOPY 32   // 32 LDS copies of the 20-bin table: 2 lanes/copy -> ~no same-address serialization

// Per element: bin = ceil((c-0.5)*40)-1 (left-open/right-closed bins, matches
// searchsorted(side='left')-1; verified absmax 0.0 in rounds 1-2).
// Valid elements do ONE ds_add_f32 of d = c - a into s_hist[copy][bin];
// invalid (c<=0.5 or c>1 -> bin as unsigned >= 20) are exec-masked off.
__global__ void ece_accum(const float4* __restrict__ confs,
                          const float4* __restrict__ accs,
                          int n4,
                          float* __restrict__ partials,  // [NBINS][nb]
                          int nb) {
    __shared__ float s_hist[NCOPY * NBINS];
    for (int i = threadIdx.x; i < NCOPY * NBINS; i += blockDim.x) s_hist[i] = 0.0f;
    __syncthreads();

    float* my = s_hist + (threadIdx.x & (NCOPY - 1)) * NBINS;

    const int tid = blockIdx.x * blockDim.x + threadIdx.x;
    const int stride = gridDim.x * blockDim.x;

#pragma unroll 2
    for (int i = tid; i < n4; i += stride) {
        float4 c4 = confs[i];
        float4 a4 = accs[i];
#pragma unroll
        for (int j = 0; j < 4; ++j) {
            float c = (j == 0) ? c4.x : (j == 1) ? c4.y : (j == 2) ? c4.z : c4.w;
            float a = (j == 0) ? a4.x : (j == 1) ? a4.y : (j == 2) ? a4.z : a4.w;
            float t = (c - 0.5f) * 40.0f;
            unsigned int bin = (unsigned int)((int)__builtin_ceilf(t) - 1);
            if (bin < (unsigned int)NBINS)
                atomicAdd(&my[bin], c - a);   // ds_add_f32, exec-masked
        }
    }
    __syncthreads();

    // reduce the 32 copies; one non-atomic partial write per bin per block
    if (threadIdx.x < NBINS) {
        const int b = threadIdx.x;
        float s = 0.0f;
#pragma unroll
        for (int k = 0; k < NCOPY; ++k) s += s_hist[k * NBINS + b];
        partials[b * nb + blockIdx.x] = s;
    }
}

// One block: reduce nb partials per bin, ece = sum_b |S_b| / N
__global__ void ece_final(const float* __restrict__ partials,
                          float* __restrict__ out,
                          float inv_n, int nb) {
    float s[NBINS];
#pragma unroll
    for (int b = 0; b < NBINS; ++b) s[b] = 0.0f;

    const int tid = threadIdx.x;
    const int nb4 = nb >> 2;  // nb is a multiple of 4
#pragma unroll
    for (int b = 0; b < NBINS; ++b) {
        const float4* pb = (const float4*)(partials + b * nb);
        for (int k = tid; k < nb4; k += blockDim.x) {
            float4 v = pb[k];
            s[b] += (v.x + v.y) + (v.z + v.w);
        }
    }
#pragma unroll
    for (int b = 0; b < NBINS; ++b) {
#pragma unroll
        for (int m = 32; m >= 1; m >>= 1)
            s[b] += __shfl_xor(s[b], m, 64);
    }

    __shared__ float red[NBINS][4];
    const int wave = tid >> 6;
    const int lane = tid & 63;
    if (lane == 0) {
#pragma unroll
        for (int b = 0; b < NBINS; ++b) red[b][wave] = s[b];
    }
    __syncthreads();

    if (tid == 0) {
        float ece = 0.0f;
#pragma unroll
        for (int b = 0; b < NBINS; ++b) {
            float t = (red[b][0] + red[b][1]) + (red[b][2] + red[b][3]);
            ece += fabsf(t);
        }
        out[0] = ece * inv_n;
    }
}

extern "C" void kernel_launch(void* const* d_in, const int* in_sizes, int n_in,
                              void* d_out, int out_size, void* d_ws, size_t ws_size,
                              hipStream_t stream) {
    const float* confs = (const float*)d_in[0];
    const float* accs = (const float*)d_in[1];
    const int n = in_sizes[0];   // 16,777,216
    const int n4 = n / 4;

    int nb = 2048;
    int ws_cap = (int)(ws_size / (NBINS * sizeof(float)));
    ws_cap &= ~3;
    if (nb > ws_cap) nb = ws_cap;
    if (nb < 4) nb = 4;

    float* partials = (float*)d_ws;

    ece_accum<<<nb, 256, 0, stream>>>((const float4*)confs, (const float4*)accs,
                                      n4, partials, nb);
    ece_final<<<1, 256, 0, stream>>>(partials, (float*)d_out, 1.0f / (float)n, nb);
}

// Round 4
// 42.060 us; speedup vs baseline: 1.5628x; 1.5628x over previous
//
#include <hip/hip_runtime.h>
#include <hip/hip_bf16.h>

#define NBINS 20
#define NSLOT 21      // slot 20 = trash for invalid samples (c<=0.5 or c>1)
#define TPB 256

// Non-atomic LDS RMW histogram: s[slot][tid] private column per thread.
// bank = (slot*256+tid)%32 = tid%32 -> 2-way lane aliasing only (free).
// bin = ceil((c-0.5)*40)-1 matches searchsorted(side='left')-1 (absmax 0.0
// verified rounds 1-3); invalid bins clamp to slot 20 via unsigned min.
__global__ __launch_bounds__(TPB) void ece_accum(
        const float4* __restrict__ confs,
        const float4* __restrict__ accs,
        int n8,                        // n/8
        float* __restrict__ partials,  // [NBINS][nb]
        int nb) {
    __shared__ float s[NSLOT * TPB];
    __shared__ float red[NBINS][TPB / 64];
    const int t = threadIdx.x;
#pragma unroll
    for (int k = 0; k < NSLOT; ++k) s[k * TPB + t] = 0.0f;
    __syncthreads();

    const int tid = blockIdx.x * TPB + t;
    const int stride = gridDim.x * TPB;

#pragma unroll 2
    for (int i = tid; i < n8; i += stride) {
        // 8 elements per thread per iteration: 2 KB contiguous per wave per stream
        float4 c4a = confs[2 * i];
        float4 c4b = confs[2 * i + 1];
        float4 a4a = accs[2 * i];
        float4 a4b = accs[2 * i + 1];
#pragma unroll
        for (int j = 0; j < 8; ++j) {
            float c, a;
            switch (j) {
                case 0: c = c4a.x; a = a4a.x; break;
                case 1: c = c4a.y; a = a4a.y; break;
                case 2: c = c4a.z; a = a4a.z; break;
                case 3: c = c4a.w; a = a4a.w; break;
                case 4: c = c4b.x; a = a4b.x; break;
                case 5: c = c4b.y; a = a4b.y; break;
                case 6: c = c4b.z; a = a4b.z; break;
                default: c = c4b.w; a = a4b.w; break;
            }
            float ft = __builtin_ceilf((c - 0.5f) * 40.0f);
            unsigned int bin = (unsigned int)((int)ft - 1);
            bin = bin < (unsigned int)NBINS ? bin : (unsigned int)NBINS;  // v_min_u32
            s[bin * TPB + t] += c - a;   // ds_read_b32 + v_add + ds_write_b32
        }
    }
    __syncthreads();

    // per-bin reduce across the 256 private columns
    const int wave = t >> 6, lane = t & 63;
#pragma unroll
    for (int b = 0; b < NBINS; ++b) {
        float v = s[b * TPB + t];
#pragma unroll
        for (int m = 32; m >= 1; m >>= 1) v += __shfl_xor(v, m, 64);
        if (lane == 0) red[b][wave] = v;
    }
    __syncthreads();
    if (t < NBINS) {
        float sum = red[t][0] + red[t][1] + red[t][2] + red[t][3];
        partials[t * nb + blockIdx.x] = sum;
    }
}

// One block, 512 threads: reduce nb partials per bin, ece = sum_b |S_b| / N
__global__ __launch_bounds__(512) void ece_final(
        const float* __restrict__ partials,
        float* __restrict__ out,
        float inv_n, int nb) {
    float s[NBINS];
#pragma unroll
    for (int b = 0; b < NBINS; ++b) s[b] = 0.0f;

    const int tid = threadIdx.x;
    const int nb4 = nb >> 2;  // nb is a multiple of 4
#pragma unroll
    for (int b = 0; b < NBINS; ++b) {
        const float4* pb = (const float4*)(partials + b * nb);
        for (int k = tid; k < nb4; k += blockDim.x) {
            float4 v = pb[k];
            s[b] += (v.x + v.y) + (v.z + v.w);
        }
    }
#pragma unroll
    for (int b = 0; b < NBINS; ++b) {
#pragma unroll
        for (int m = 32; m >= 1; m >>= 1)
            s[b] += __shfl_xor(s[b], m, 64);
    }

    __shared__ float red[NBINS][8];
    const int wave = tid >> 6;
    const int lane = tid & 63;
    if (lane == 0) {
#pragma unroll
        for (int b = 0; b < NBINS; ++b) red[b][wave] = s[b];
    }
    __syncthreads();

    if (tid == 0) {
        float ece = 0.0f;
#pragma unroll
        for (int b = 0; b < NBINS; ++b) {
            float t = 0.0f;
#pragma unroll
            for (int w = 0; w < 8; ++w) t += red[b][w];
            ece += fabsf(t);
        }
        out[0] = ece * inv_n;
    }
}

extern "C" void kernel_launch(void* const* d_in, const int* in_sizes, int n_in,
                              void* d_out, int out_size, void* d_ws, size_t ws_size,
                              hipStream_t stream) {
    const float* confs = (const float*)d_in[0];
    const float* accs = (const float*)d_in[1];
    const int n = in_sizes[0];   // 16,777,216
    const int n8 = n / 8;

    // 7 blocks/CU at 21.8 KB LDS -> 1792 blocks = full single-shot residency
    int nb = 1792;
    int ws_cap = (int)(ws_size / (NBINS * sizeof(float)));
    ws_cap &= ~3;
    if (nb > ws_cap) nb = ws_cap;
    if (nb < 4) nb = 4;

    float* partials = (float*)d_ws;

    ece_accum<<<nb, TPB, 0, stream>>>((const float4*)confs, (const float4*)accs,
                                      n8, partials, nb);
    ece_final<<<1, 512, 0, stream>>>(partials, (float*)d_out, 1.0f / (float)n, nb);
}